// Round 1
// baseline (196.522 us; speedup 1.0000x reference)
//
#include <hip/hip_runtime.h>
#include <math.h>

#define G 8  // images per block (256 threads, 32 threads/image)

// Bit-exact replication of the reference's s_eff (forward value of LSQ scale):
//   g  = 1/sqrt(n*qp)  computed in double (Python float), cast to f32 (JAX weak scalar)
//   sg = s*g (f32);  s_eff = sg + (s - sg) (f32)
__device__ __forceinline__ float seff(float s, double nqp) {
    float g  = (float)(1.0 / sqrt(nqp));
    float sg = s * g;
    return sg + (s - sg);
}

// clip(x/s, lo, hi) then round-half-even — matches jnp.clip + jnp.round (STE fwd)
__device__ __forceinline__ float quantf(float v, float s, float lo, float hi) {
    return rintf(fminf(fmaxf(v / s, lo), hi));
}

extern "C" __global__ __launch_bounds__(256)
void qcnn_fused(const float* __restrict__ x,  const float* __restrict__ w1,
                const float* __restrict__ w2, const float* __restrict__ fcw,
                const float* __restrict__ fcb,
                const float* __restrict__ s_in, const float* __restrict__ s_w1,
                const float* __restrict__ s_a1, const float* __restrict__ s_w2,
                const float* __restrict__ s_a2, const float* __restrict__ s_fc,
                float* __restrict__ out, int B)
{
    // integer-valued f32 tensors (scales factored out into r1/r2/r3)
    __shared__ float xs [G][784];      // 28x28 quantized input, rows = 112B (16B aligned)
    __shared__ float a1s[G][4][144];   // 4 x 12x12, rows = 48B
    __shared__ float a2s[G][200];
    __shared__ float w1s[4][25];
    __shared__ float w2s[8][4][9];
    __shared__ float fcs[10][200];
    __shared__ float fcbs[10];

    const int tid = threadIdx.x;
    const int g   = tid >> 5;   // image slot within block
    const int t   = tid & 31;   // lane within image group
    const long long b0 = (long long)blockIdx.x * G;
    const int nimg = (B - (int)b0 < G) ? (B - (int)b0) : G;

    // --- scales (exact f32 replication) + f64 ratios for quant decisions ---
    const float sx  = seff(s_in[0], (double)B * 784.0 * 127.0);
    const float sw1 = seff(s_w1[0], 100.0 * 127.0);
    const float sa1 = seff(s_a1[0], (double)B * 576.0 * 255.0);
    const float sw2 = seff(s_w2[0], 288.0 * 127.0);
    const float sa2 = seff(s_a2[0], (double)B * 200.0 * 255.0);
    const float sfc = seff(s_fc[0], 2000.0 * 127.0);
    const double r1 = (double)sx  * (double)sw1 / (double)sa1;
    const double r2 = (double)sa1 * (double)sw2 / (double)sa2;
    const double r3 = (double)sa2 * (double)sfc;

    // --- stage + quantize x (coalesced float4; exact f32 div + rintf) ---
    {
        const float4* xg = (const float4*)(x + b0 * 784);
        float4*       xl = (float4*)&xs[0][0];
        const int nv = nimg * 196;
        for (int i = tid; i < nv; i += 256) {
            float4 v = xg[i], q;
            q.x = quantf(v.x, sx, -128.f, 127.f);
            q.y = quantf(v.y, sx, -128.f, 127.f);
            q.z = quantf(v.z, sx, -128.f, 127.f);
            q.w = quantf(v.w, sx, -128.f, 127.f);
            xl[i] = q;
        }
    }
    // --- stage + quantize weights (tiny; recomputed per block, L2-cached) ---
    if (tid < 100) ((float*)w1s)[tid] = quantf(w1[tid], sw1, -128.f, 127.f);
    for (int i = tid; i < 288; i += 256)
        ((float*)w2s)[i] = quantf(w2[i], sw2, -128.f, 127.f);
    for (int i = tid; i < 2000; i += 256)
        ((float*)fcs)[i] = quantf(fcw[i], sfc, -128.f, 127.f);
    if (tid < 10) fcbs[tid] = fcb[tid];
    __syncthreads();

    // --- conv1: 5x5 s2, 1->4 ch, out 12x12. task = (row y, channel-pair) ---
    if (g < nimg && t < 24) {
        const int y  = t >> 1;
        const int c0 = (t & 1) << 1;   // channels c0, c0+1
        float acc[2][12];
        #pragma unroll
        for (int j = 0; j < 12; ++j) { acc[0][j] = 0.f; acc[1][j] = 0.f; }
        #pragma unroll
        for (int ky = 0; ky < 5; ++ky) {
            float r[28];
            const float4* row4 = (const float4*)&xs[g][(2*y + ky) * 28];
            #pragma unroll
            for (int q = 0; q < 7; ++q) {
                float4 v = row4[q];
                r[4*q] = v.x; r[4*q+1] = v.y; r[4*q+2] = v.z; r[4*q+3] = v.w;
            }
            #pragma unroll
            for (int kx = 0; kx < 5; ++kx) {
                const float wa = w1s[c0][ky*5 + kx];
                const float wb = w1s[c0+1][ky*5 + kx];
                #pragma unroll
                for (int j = 0; j < 12; ++j) {
                    acc[0][j] += wa * r[2*j + kx];   // exact integer f32 math
                    acc[1][j] += wb * r[2*j + kx];
                }
            }
        }
        #pragma unroll
        for (int c = 0; c < 2; ++c)
            #pragma unroll
            for (int j = 0; j < 12; ++j) {
                double v = (double)acc[c][j] * r1;        // f64 decides ties
                v = fmin(fmax(v, 0.0), 255.0);            // clip then round
                a1s[g][c0 + c][y*12 + j] = (float)rint(v); // relu is a no-op
            }
    }
    __syncthreads();

    // --- conv2: 3x3 s2, 4->8 ch, out 5x5. task = (row y, 4-out-ch group) ---
    if (g < nimg && t < 10) {
        const int y  = t % 5;
        const int oq = (t / 5) * 4;    // out-channels oq..oq+3
        float acc[4][5];
        #pragma unroll
        for (int oc = 0; oc < 4; ++oc)
            #pragma unroll
            for (int j = 0; j < 5; ++j) acc[oc][j] = 0.f;
        #pragma unroll
        for (int ic = 0; ic < 4; ++ic) {
            #pragma unroll
            for (int ky = 0; ky < 3; ++ky) {
                float r[12];
                const float4* row4 = (const float4*)&a1s[g][ic][(2*y + ky) * 12];
                #pragma unroll
                for (int q = 0; q < 3; ++q) {
                    float4 v = row4[q];
                    r[4*q] = v.x; r[4*q+1] = v.y; r[4*q+2] = v.z; r[4*q+3] = v.w;
                }
                #pragma unroll
                for (int kx = 0; kx < 3; ++kx) {
                    #pragma unroll
                    for (int oc = 0; oc < 4; ++oc) {
                        const float w = w2s[oq + oc][ic][ky*3 + kx];
                        #pragma unroll
                        for (int j = 0; j < 5; ++j)
                            acc[oc][j] += w * r[2*j + kx];
                    }
                }
            }
        }
        #pragma unroll
        for (int oc = 0; oc < 4; ++oc)
            #pragma unroll
            for (int j = 0; j < 5; ++j) {
                double v = (double)acc[oc][j] * r2;
                v = fmin(fmax(v, 0.0), 255.0);
                a2s[g][(oq + oc)*25 + y*5 + j] = (float)rint(v);
            }
    }
    __syncthreads();

    // --- FC: [200] -> [10]; integer dot exact in f32 (<= 6.5M < 2^24) ---
    if (g < nimg && t < 10) {
        float acc = 0.f;
        const float4* av = (const float4*)&a2s[g][0];
        const float4* wv = (const float4*)&fcs[t][0];
        #pragma unroll
        for (int k = 0; k < 50; ++k) {
            float4 a = av[k], w = wv[k];
            acc += a.x*w.x + a.y*w.y + a.z*w.z + a.w*w.w;
        }
        double o = (double)acc * r3 + (double)fcbs[t];
        out[(b0 + g)*10 + t] = (float)o;
    }
}

extern "C" void kernel_launch(void* const* d_in, const int* in_sizes, int n_in,
                              void* d_out, int out_size, void* d_ws, size_t ws_size,
                              hipStream_t stream) {
    const float* x   = (const float*)d_in[0];
    const float* w1  = (const float*)d_in[1];
    const float* w2  = (const float*)d_in[2];
    const float* fcw = (const float*)d_in[3];
    const float* fcb = (const float*)d_in[4];
    const float* s_in = (const float*)d_in[5];
    const float* s_w1 = (const float*)d_in[6];
    const float* s_a1 = (const float*)d_in[7];
    const float* s_w2 = (const float*)d_in[8];
    const float* s_a2 = (const float*)d_in[9];
    const float* s_fc = (const float*)d_in[10];

    const int B = in_sizes[0] / 784;          // 65536
    const int grid = (B + G - 1) / G;         // 8192 blocks
    qcnn_fused<<<grid, 256, 0, stream>>>(x, w1, w2, fcw, fcb,
                                         s_in, s_w1, s_a1, s_w2, s_a2, s_fc,
                                         (float*)d_out, B);
}

// Round 2
// 84.937 us; speedup vs baseline: 2.3137x; 2.3137x over previous
//
#include <hip/hip_runtime.h>
#include <math.h>

#define G 8  // images per block (256 threads; 32-thread group per image)

// ---- int8 dot4: D = c + sum(a.i8[i] * b.i8[i]) -------------------------
#if __has_builtin(__builtin_amdgcn_sdot4)
__device__ __forceinline__ int dot4(unsigned a, unsigned b, int c) {
    return __builtin_amdgcn_sdot4((int)a, (int)b, c, false);
}
#else
__device__ __forceinline__ int dot4(unsigned a, unsigned b, int c) {
    c += (int)(signed char)(a & 255u)         * (int)(signed char)(b & 255u);
    c += (int)(signed char)((a >> 8) & 255u)  * (int)(signed char)((b >> 8) & 255u);
    c += (int)(signed char)((a >> 16) & 255u) * (int)(signed char)((b >> 16) & 255u);
    c += (int)(signed char)(a >> 24)          * (int)(signed char)(b >> 24);
    return c;
}
#endif

// LSQ forward scale, bit-exact vs reference: sg = s*g; s_eff = sg + (s - sg)
__device__ __forceinline__ float seff(float s, float gf) {
    float sg = s * gf;
    return sg + (s - sg);
}
// clip(x/s, lo, hi) then round-half-even — exact f32 div matches jnp/np
__device__ __forceinline__ float quantf(float v, float s, float lo, float hi) {
    return rintf(fminf(fmaxf(v / s, lo), hi));
}
__device__ __forceinline__ int quanti(float v, float s, float lo, float hi) {
    return (int)quantf(v, s, lo, hi);
}

extern "C" __global__ __launch_bounds__(256, 4)
void qcnn_fused(const float* __restrict__ x,  const float* __restrict__ w1,
                const float* __restrict__ w2, const float* __restrict__ fcw,
                const float* __restrict__ fcb,
                const float* __restrict__ s_in, const float* __restrict__ s_w1,
                const float* __restrict__ s_a1, const float* __restrict__ s_w2,
                const float* __restrict__ s_a2, const float* __restrict__ s_fc,
                float* __restrict__ out, int B,
                float gx, float gw1, float ga1, float gw2, float ga2, float gfc)
{
    // byte-packed integer tensors
    __shared__ unsigned xs [G*196];      // x quantized i8, 28B rows = 7 dwords
    __shared__ unsigned a1p[G*144];      // per pixel: 4 ic bytes of (a1-128)
    __shared__ unsigned a2p[G*50];       // flat 200 bytes of (a2-128) per image
    __shared__ unsigned w1pk[4][5][4];   // per ch,ky: evenA,evenB,oddA,oddB packs
    __shared__ unsigned w2p[8][9];       // per oc,tap: 4 ic bytes
    __shared__ unsigned fcp[10][50];     // fc weights i8 packed along k
    __shared__ int K2[8];                // 128*sum(w2q[oc])
    __shared__ int K3[10];               // 128*sum(fcq[o])
    __shared__ float fcbs[10];

    const int tid = threadIdx.x;
    const int g   = tid >> 5;
    const int t   = tid & 31;
    const long long b0 = (long long)blockIdx.x * G;
    const int nimg = (B - (int)b0 < G) ? (B - (int)b0) : G;

    // scales: exact f32 replication; quant-decision ratios in f64 (same as R1)
    const float sx  = seff(s_in[0], gx);
    const float sw1 = seff(s_w1[0], gw1);
    const float sa1 = seff(s_a1[0], ga1);
    const float sw2 = seff(s_w2[0], gw2);
    const float sa2 = seff(s_a2[0], ga2);
    const float sfc = seff(s_fc[0], gfc);
    const double r1 = (double)sx  * (double)sw1 / (double)sa1;
    const double r2 = (double)sa1 * (double)sw2 / (double)sa2;
    const double r3 = (double)sa2 * (double)sfc;

    // ---------------- phase A: stage x (quant -> i8 pack) + weights -------
    {
        const float4* xg = (const float4*)(x + b0 * 784);
        const int nv = nimg * 196;
        for (int i = tid; i < nv; i += 256) {
            float4 v = xg[i];
            const int a = quanti(v.x, sx, -128.f, 127.f);
            const int b = quanti(v.y, sx, -128.f, 127.f);
            const int c = quanti(v.z, sx, -128.f, 127.f);
            const int d = quanti(v.w, sx, -128.f, 127.f);
            xs[i] = (unsigned)(a & 255) | ((unsigned)(b & 255) << 8) |
                    ((unsigned)(c & 255) << 16) | ((unsigned)d << 24);
        }
    }
    if (tid < 80) {                       // w1 packs: 4ch x 5ky x 4 variants
        const int c = tid / 20, rem = tid % 20, ky = rem >> 2, vv = rem & 3;
        const float* wr = w1 + c*25 + ky*5;
        unsigned b[5];
        #pragma unroll
        for (int k = 0; k < 5; ++k)
            b[k] = (unsigned)(quanti(wr[k], sw1, -128.f, 127.f) & 255);
        unsigned pk;
        if      (vv == 0) pk = b[0] | (b[1] << 8) | (b[2] << 16) | (b[3] << 24);
        else if (vv == 1) pk = b[4];
        else if (vv == 2) pk = (b[0] << 16) | (b[1] << 24);
        else              pk = b[2] | (b[3] << 8) | (b[4] << 16);
        w1pk[c][ky][vv] = pk;
    } else if (tid < 152) {               // w2 packs: 8oc x 9taps, ic-bytes
        const int d = tid - 80, oc = d / 9, tap = d % 9;
        unsigned pk = 0;
        #pragma unroll
        for (int ic = 0; ic < 4; ++ic)
            pk |= (unsigned)(quanti(w2[oc*36 + ic*9 + tap], sw2, -128.f, 127.f) & 255) << (8*ic);
        w2p[oc][tap] = pk;
    }
    if (tid < 10) fcbs[tid] = fcb[tid];
    for (int i = tid; i < 500; i += 256) { // fc packs: 10 x 50 dwords
        const int o = i / 50, kd = i % 50;
        const float* fr = fcw + o*200 + kd*4;
        unsigned pk = 0;
        #pragma unroll
        for (int k = 0; k < 4; ++k)
            pk |= (unsigned)(quanti(fr[k], sfc, -128.f, 127.f) & 255) << (8*k);
        fcp[o][kd] = pk;
    }
    __syncthreads();

    // ---------------- phase B: conv1 (t<24) + K2/K3 sums (t>=24) ----------
    if (t >= 24) {
        const int slot = g * 8 + (t - 24);     // 0..63
        if (slot < 8) {                        // K2[oc]
            int s = 0;
            #pragma unroll
            for (int d = 0; d < 9; ++d) s = dot4(w2p[slot][d], 0x01010101u, s);
            K2[slot] = s << 7;
        } else if (slot < 18) {                // K3[o]
            const int o = slot - 8;
            int s = 0;
            for (int d = 0; d < 50; ++d) s = dot4(fcp[o][d], 0x01010101u, s);
            K3[o] = s << 7;
        }
    } else if (g < nimg) {
        // lane = (y, channel-pair): 12 rows x 2 pairs = 24 lanes
        const int y  = t >> 1;
        const int c0 = (t & 1) << 1;
        int acc[2][12];
        #pragma unroll
        for (int c = 0; c < 2; ++c)
            #pragma unroll
            for (int j = 0; j < 12; ++j) acc[c][j] = 0;
        #pragma unroll
        for (int ky = 0; ky < 5; ++ky) {
            unsigned row[7];
            const unsigned* rp = &xs[g*196 + (2*y + ky)*7];
            #pragma unroll
            for (int d = 0; d < 7; ++d) row[d] = rp[d];
            #pragma unroll
            for (int c = 0; c < 2; ++c) {
                const unsigned pEA = w1pk[c0+c][ky][0];
                const unsigned pEB = w1pk[c0+c][ky][1];
                const unsigned pOA = w1pk[c0+c][ky][2];
                const unsigned pOB = w1pk[c0+c][ky][3];
                #pragma unroll
                for (int j = 0; j < 12; ++j) {
                    const int lo = j >> 1;   // window byte 2j: even j aligned 0, odd j aligned 2
                    if (j & 1) {
                        acc[c][j] = dot4(row[lo],   pOA, acc[c][j]);
                        acc[c][j] = dot4(row[lo+1], pOB, acc[c][j]);
                    } else {
                        acc[c][j] = dot4(row[lo],   pEA, acc[c][j]);
                        acc[c][j] = dot4(row[lo+1], pEB, acc[c][j]);
                    }
                }
            }
        }
        int q[2][12];
        #pragma unroll
        for (int c = 0; c < 2; ++c)
            #pragma unroll
            for (int j = 0; j < 12; ++j) {
                double v = (double)acc[c][j] * r1;   // f64 decides ties (as R1)
                v = fmin(fmax(v, 0.0), 255.0);
                q[c][j] = (int)rint(v);
            }
        #pragma unroll
        for (int j = 0; j < 12; ++j) {   // store (a1-128) i8 pair for ch c0,c0+1
            const unsigned short h =
                (unsigned short)(((q[0][j] - 128) & 255) | (((q[1][j] - 128) & 255) << 8));
            ((unsigned short*)a1p)[(g*144 + y*12 + j)*2 + (c0 >> 1)] = h;
        }
    }
    __syncthreads();

    // ---------------- phase C: conv2, lane = (oc, quarter-of-25-pixels) ---
    if (g < nimg) {
        const int oc   = t >> 2;
        const int part = t & 3;
        const int p0   = part ? (1 + 6*part) : 0;    // {0,7,13,19}
        const int np   = part ? 6 : 7;
        unsigned wv[9];
        #pragma unroll
        for (int d = 0; d < 9; ++d) wv[d] = w2p[oc][d];
        const int k2 = K2[oc];
        const unsigned* base = &a1p[g*144];
        for (int pi = 0; pi < np; ++pi) {
            const int p = p0 + pi;
            const int y = p / 5, jx = p - y*5;
            int acc = k2;                  // +128*sum(w) offsets the -128 bias
            #pragma unroll
            for (int ky = 0; ky < 3; ++ky)
                #pragma unroll
                for (int kx = 0; kx < 3; ++kx)
                    acc = dot4(base[(2*y + ky)*12 + (2*jx + kx)], wv[ky*3 + kx], acc);
            double v = (double)acc * r2;
            v = fmin(fmax(v, 0.0), 255.0);
            const int iv = (int)rint(v);
            ((unsigned char*)a2p)[g*200 + oc*25 + p] = (unsigned char)(iv - 128);
        }
    }
    __syncthreads();

    // ---------------- phase D: FC, lane = (o, third-of-50-dwords) ---------
    if (g < nimg && t < 30) {
        const int part = t / 10;
        const int o    = t - part*10;
        const int k0   = part * 17;
        const int nk   = (part == 2) ? 16 : 17;
        int acc = 0;
        for (int ki = 0; ki < nk; ++ki) {
            const int k = k0 + ki;
            acc = dot4(a2p[g*50 + k], fcp[o][k], acc);
        }
        const int self0 = (g & 1) * 32 + o;          // wave-lane holding part 0
        const int s1 = __shfl(acc, self0 + 10);
        const int s2 = __shfl(acc, self0 + 20);
        if (part == 0) {
            const int total = acc + s1 + s2 + K3[o];
            const double oo = (double)total * r3 + (double)fcbs[o];
            out[(b0 + g)*10 + o] = (float)oo;
        }
    }
}

extern "C" void kernel_launch(void* const* d_in, const int* in_sizes, int n_in,
                              void* d_out, int out_size, void* d_ws, size_t ws_size,
                              hipStream_t stream) {
    const float* x    = (const float*)d_in[0];
    const float* w1   = (const float*)d_in[1];
    const float* w2   = (const float*)d_in[2];
    const float* fcw  = (const float*)d_in[3];
    const float* fcb  = (const float*)d_in[4];
    const float* s_in = (const float*)d_in[5];
    const float* s_w1 = (const float*)d_in[6];
    const float* s_a1 = (const float*)d_in[7];
    const float* s_w2 = (const float*)d_in[8];
    const float* s_a2 = (const float*)d_in[9];
    const float* s_fc = (const float*)d_in[10];

    const int B = in_sizes[0] / 784;          // 65536
    // grad-scale factors g = 1/sqrt(n*qp), double->float exactly as reference
    const float gx  = (float)(1.0 / sqrt((double)B * 784.0 * 127.0));
    const float gw1 = (float)(1.0 / sqrt(100.0 * 127.0));
    const float ga1 = (float)(1.0 / sqrt((double)B * 576.0 * 255.0));
    const float gw2 = (float)(1.0 / sqrt(288.0 * 127.0));
    const float ga2 = (float)(1.0 / sqrt((double)B * 200.0 * 255.0));
    const float gfc = (float)(1.0 / sqrt(2000.0 * 127.0));

    const int grid = (B + G - 1) / G;         // 8192 blocks
    qcnn_fused<<<grid, 256, 0, stream>>>(x, w1, w2, fcw, fcb,
                                         s_in, s_w1, s_a1, s_w2, s_a2, s_fc,
                                         (float*)d_out, B,
                                         gx, gw1, ga1, gw2, ga2, gfc);
}

// Round 3
// 69.362 us; speedup vs baseline: 2.8333x; 1.2246x over previous
//
#include <hip/hip_runtime.h>
#include <math.h>

#define G 8  // images per block (256 threads; 32-thread group per image)

// ---- int8 dot4: D = c + sum(a.i8[i] * b.i8[i]) -------------------------
#if __has_builtin(__builtin_amdgcn_sdot4)
__device__ __forceinline__ int dot4(unsigned a, unsigned b, int c) {
    return __builtin_amdgcn_sdot4((int)a, (int)b, c, false);
}
#else
__device__ __forceinline__ int dot4(unsigned a, unsigned b, int c) {
    c += (int)(signed char)(a & 255u)         * (int)(signed char)(b & 255u);
    c += (int)(signed char)((a >> 8) & 255u)  * (int)(signed char)((b >> 8) & 255u);
    c += (int)(signed char)((a >> 16) & 255u) * (int)(signed char)((b >> 16) & 255u);
    c += (int)(signed char)(a >> 24)          * (int)(signed char)(b >> 24);
    return c;
}
#endif

// LSQ forward scale, bit-exact vs reference: sg = s*g; s_eff = sg + (s - sg)
__device__ __forceinline__ float seff(float s, float gf) {
    float sg = s * gf;
    return sg + (s - sg);
}
// Markstein correctly-rounded division: rs = RN(1/s) precomputed.
// q0=RN(v*rs); r=v-s*q0 (exact, FMA); q=RN(q0+r*rs) == RN(v/s).
__device__ __forceinline__ float fdiv_exact(float v, float s, float rs) {
    float q0 = v * rs;
    float r  = fmaf(-s, q0, v);
    return fmaf(r, rs, q0);
}
// quant to int: rint(v/s) then clamp (== clamp-then-rint at integer bounds)
__device__ __forceinline__ int qidx(float v, float s, float rs, int lo, int hi) {
    int qi = (int)rintf(fdiv_exact(v, s, rs));
    return min(max(qi, lo), hi);
}

extern "C" __global__ __launch_bounds__(256, 4)
void qcnn_fused(const float* __restrict__ x,  const float* __restrict__ w1,
                const float* __restrict__ w2, const float* __restrict__ fcw,
                const float* __restrict__ fcb,
                const float* __restrict__ s_in, const float* __restrict__ s_w1,
                const float* __restrict__ s_a1, const float* __restrict__ s_w2,
                const float* __restrict__ s_a2, const float* __restrict__ s_fc,
                float* __restrict__ out, int B,
                float gx, float gw1, float ga1, float gw2, float ga2, float gfc)
{
    // byte-packed integer tensors
    __shared__ unsigned xs [G*196];      // x quantized i8, 28B rows = 7 dwords
    __shared__ unsigned a1p[G*144];      // per pixel: 4 ic bytes of (a1-128)
    __shared__ unsigned a2p[G*50];       // flat 200 bytes of (a2-128), oc-major
    __shared__ unsigned w1pk[4][5][4];   // per ch,ky: evenA,evenB,oddA,oddB packs
    __shared__ unsigned w2p[8][9];       // per oc,tap: 4 ic bytes
    __shared__ unsigned fcp[10][50];     // fc weights i8 packed along k
    __shared__ int K2[8];                // 128*sum(w2q[oc])
    __shared__ int K3[10];               // 128*sum(fcq[o])
    __shared__ float fcbs[10];

    const int tid = threadIdx.x;
    const int g   = tid >> 5;
    const int t   = tid & 31;
    const long long b0 = (long long)blockIdx.x * G;
    const int nimg = (B - (int)b0 < G) ? (B - (int)b0) : G;

    // scales: exact f32 replication of reference forward values
    const float sx  = seff(s_in[0], gx);
    const float sw1 = seff(s_w1[0], gw1);
    const float sa1 = seff(s_a1[0], ga1);
    const float sw2 = seff(s_w2[0], gw2);
    const float sa2 = seff(s_a2[0], ga2);
    const float sfc = seff(s_fc[0], gfc);
    const float rsx = 1.0f / sx;         // correctly-rounded reciprocals
    const float rw1 = 1.0f / sw1;
    const float rw2 = 1.0f / sw2;
    const float rfc = 1.0f / sfc;

    // ---------------- phase A: stage x (quant -> i8 pack) + weights -------
    {
        const float4* xg = (const float4*)(x + b0 * 784);
        const int nv = nimg * 196;
        for (int i = tid; i < nv; i += 256) {
            float4 v = xg[i];
            const int a = qidx(v.x, sx, rsx, -128, 127);
            const int b = qidx(v.y, sx, rsx, -128, 127);
            const int c = qidx(v.z, sx, rsx, -128, 127);
            const int d = qidx(v.w, sx, rsx, -128, 127);
            xs[i] = (unsigned)(a & 255) | ((unsigned)(b & 255) << 8) |
                    ((unsigned)(c & 255) << 16) | ((unsigned)d << 24);
        }
    }
    if (tid < 80) {                       // w1 packs: 4ch x 5ky x 4 variants
        const int c = tid / 20, rem = tid % 20, ky = rem >> 2, vv = rem & 3;
        const float* wr = w1 + c*25 + ky*5;
        unsigned b[5];
        #pragma unroll
        for (int k = 0; k < 5; ++k)
            b[k] = (unsigned)(qidx(wr[k], sw1, rw1, -128, 127) & 255);
        unsigned pk;
        if      (vv == 0) pk = b[0] | (b[1] << 8) | (b[2] << 16) | (b[3] << 24);
        else if (vv == 1) pk = b[4];
        else if (vv == 2) pk = (b[0] << 16) | (b[1] << 24);
        else              pk = b[2] | (b[3] << 8) | (b[4] << 16);
        w1pk[c][ky][vv] = pk;
    } else if (tid < 152) {               // w2 packs: 8oc x 9taps, ic-bytes
        const int d = tid - 80, oc = d / 9, tap = d % 9;
        unsigned pk = 0;
        #pragma unroll
        for (int ic = 0; ic < 4; ++ic)
            pk |= (unsigned)(qidx(w2[oc*36 + ic*9 + tap], sw2, rw2, -128, 127) & 255) << (8*ic);
        w2p[oc][tap] = pk;
    }
    if (tid < 10) fcbs[tid] = fcb[tid];
    for (int i = tid; i < 500; i += 256) { // fc packs: 10 x 50 dwords
        const int o = i / 50, kd = i % 50;
        const float* fr = fcw + o*200 + kd*4;
        unsigned pk = 0;
        #pragma unroll
        for (int k = 0; k < 4; ++k)
            pk |= (unsigned)(qidx(fr[k], sfc, rfc, -128, 127) & 255) << (8*k);
        fcp[o][kd] = pk;
    }
    __syncthreads();

    // ---------------- phase B: conv1 (t<24) + K2/K3 sums (t>=24) ----------
    if (t >= 24) {
        const int slot = g * 8 + (t - 24);     // 0..63
        if (slot < 8) {                        // K2[oc]
            int s = 0;
            #pragma unroll
            for (int d = 0; d < 9; ++d) s = dot4(w2p[slot][d], 0x01010101u, s);
            K2[slot] = s << 7;
        } else if (slot < 18) {                // K3[o]
            const int o = slot - 8;
            int s = 0;
            for (int d = 0; d < 50; ++d) s = dot4(fcp[o][d], 0x01010101u, s);
            K3[o] = s << 7;
        }
    } else if (g < nimg) {
        const double r1 = (double)sx * (double)sw1 / (double)sa1;
        // lane = (y, channel-pair): 12 rows x 2 pairs = 24 lanes
        const int y  = t >> 1;
        const int c0 = (t & 1) << 1;
        int acc[2][12];
        #pragma unroll
        for (int c = 0; c < 2; ++c)
            #pragma unroll
            for (int j = 0; j < 12; ++j) acc[c][j] = 0;
        #pragma unroll
        for (int ky = 0; ky < 5; ++ky) {
            unsigned row[7];
            const unsigned* rp = &xs[g*196 + (2*y + ky)*7];
            #pragma unroll
            for (int d = 0; d < 7; ++d) row[d] = rp[d];
            #pragma unroll
            for (int c = 0; c < 2; ++c) {
                const unsigned pEA = w1pk[c0+c][ky][0];
                const unsigned pEB = w1pk[c0+c][ky][1];
                const unsigned pOA = w1pk[c0+c][ky][2];
                const unsigned pOB = w1pk[c0+c][ky][3];
                #pragma unroll
                for (int j = 0; j < 12; ++j) {
                    const int lo = j >> 1;
                    if (j & 1) {
                        acc[c][j] = dot4(row[lo],   pOA, acc[c][j]);
                        acc[c][j] = dot4(row[lo+1], pOB, acc[c][j]);
                    } else {
                        acc[c][j] = dot4(row[lo],   pEA, acc[c][j]);
                        acc[c][j] = dot4(row[lo+1], pEB, acc[c][j]);
                    }
                }
            }
        }
        int q[2][12];
        #pragma unroll
        for (int c = 0; c < 2; ++c)
            #pragma unroll
            for (int j = 0; j < 12; ++j) {
                double v = (double)acc[c][j] * r1;       // f64 decides ties
                int qi = (int)rint(v);
                q[c][j] = min(max(qi, 0), 255);          // == clip-then-rint
            }
        #pragma unroll
        for (int j = 0; j < 12; ++j) {   // store (a1-128) i8 pair for ch c0,c0+1
            const unsigned short h =
                (unsigned short)(((q[0][j] - 128) & 255) | (((q[1][j] - 128) & 255) << 8));
            ((unsigned short*)a1p)[(g*144 + y*12 + j)*2 + (c0 >> 1)] = h;
        }
    }
    __syncthreads();

    // ------- phase C: conv2, block-wide tasks (img, oc, row): G*40 --------
    {
        const double r2 = (double)sa1 * (double)sw2 / (double)sa2;
        for (int tau = tid; tau < G*40; tau += 256) {
            const int img = tau / 40;
            const int rem = tau - img*40;
            const int oc  = rem / 5;
            const int y   = rem - oc*5;
            if (img >= nimg) break;
            unsigned wv[9];
            #pragma unroll
            for (int d = 0; d < 9; ++d) wv[d] = w2p[oc][d];
            const int k2 = K2[oc];
            const unsigned* base = &a1p[img*144];
            unsigned rw[3][12];
            #pragma unroll
            for (int ky = 0; ky < 3; ++ky) {
                const uint4* rp = (const uint4*)&base[(2*y + ky)*12]; // 16B aligned
                uint4 A = rp[0], Bv = rp[1], Cv = rp[2];
                rw[ky][0]=A.x;  rw[ky][1]=A.y;  rw[ky][2]=A.z;  rw[ky][3]=A.w;
                rw[ky][4]=Bv.x; rw[ky][5]=Bv.y; rw[ky][6]=Bv.z; rw[ky][7]=Bv.w;
                rw[ky][8]=Cv.x; rw[ky][9]=Cv.y; rw[ky][10]=Cv.z; rw[ky][11]=Cv.w;
            }
            unsigned char* dst = (unsigned char*)a2p + img*200 + oc*25 + y*5;
            #pragma unroll
            for (int jx = 0; jx < 5; ++jx) {
                int acc = k2;              // +128*sum(w) offsets the -128 bias
                #pragma unroll
                for (int ky = 0; ky < 3; ++ky)
                    #pragma unroll
                    for (int kx = 0; kx < 3; ++kx)
                        acc = dot4(rw[ky][2*jx + kx], wv[ky*3 + kx], acc);
                double v = (double)acc * r2;
                int qi = (int)rint(v);
                qi = min(max(qi, 0), 255);
                dst[jx] = (unsigned char)(qi - 128);
            }
        }
    }
    __syncthreads();

    // ---------------- phase D: FC, lane = (o, third-of-50-dwords) ---------
    if (g < nimg && t < 30) {
        const double r3 = (double)sa2 * (double)sfc;
        const int part = t / 10;
        const int o    = t - part*10;
        const int k0   = part * 17;
        const int nk   = (part == 2) ? 16 : 17;
        int acc = 0;
        for (int ki = 0; ki < nk; ++ki) {
            const int k = k0 + ki;
            acc = dot4(a2p[g*50 + k], fcp[o][k], acc);
        }
        const int self0 = (g & 1) * 32 + o;          // wave-lane holding part 0
        const int s1 = __shfl(acc, self0 + 10);
        const int s2 = __shfl(acc, self0 + 20);
        if (part == 0) {
            const int total = acc + s1 + s2 + K3[o];
            const double oo = (double)total * r3 + (double)fcbs[o];
            out[(b0 + g)*10 + o] = (float)oo;
        }
    }
}

extern "C" void kernel_launch(void* const* d_in, const int* in_sizes, int n_in,
                              void* d_out, int out_size, void* d_ws, size_t ws_size,
                              hipStream_t stream) {
    const float* x    = (const float*)d_in[0];
    const float* w1   = (const float*)d_in[1];
    const float* w2   = (const float*)d_in[2];
    const float* fcw  = (const float*)d_in[3];
    const float* fcb  = (const float*)d_in[4];
    const float* s_in = (const float*)d_in[5];
    const float* s_w1 = (const float*)d_in[6];
    const float* s_a1 = (const float*)d_in[7];
    const float* s_w2 = (const float*)d_in[8];
    const float* s_a2 = (const float*)d_in[9];
    const float* s_fc = (const float*)d_in[10];

    const int B = in_sizes[0] / 784;          // 65536
    // grad-scale factors g = 1/sqrt(n*qp), double->float exactly as reference
    const float gx  = (float)(1.0 / sqrt((double)B * 784.0 * 127.0));
    const float gw1 = (float)(1.0 / sqrt(100.0 * 127.0));
    const float ga1 = (float)(1.0 / sqrt((double)B * 576.0 * 255.0));
    const float gw2 = (float)(1.0 / sqrt(288.0 * 127.0));
    const float ga2 = (float)(1.0 / sqrt((double)B * 200.0 * 255.0));
    const float gfc = (float)(1.0 / sqrt(2000.0 * 127.0));

    const int grid = (B + G - 1) / G;         // 8192 blocks
    qcnn_fused<<<grid, 256, 0, stream>>>(x, w1, w2, fcw, fcb,
                                         s_in, s_w1, s_a1, s_w2, s_a2, s_fc,
                                         (float*)d_out, B,
                                         gx, gw1, ga1, gw2, ga2, gfc);
}

// Round 4
// 64.054 us; speedup vs baseline: 3.0680x; 1.0829x over previous
//
#include <hip/hip_runtime.h>
#include <math.h>

#define G  8   // images per group (32 threads/image, 256-thread block)
#define NG 4   // groups per block (persistent loop)

// ---- int8 dot4: D = c + sum(a.i8[i] * b.i8[i]) -------------------------
#if __has_builtin(__builtin_amdgcn_sdot4)
__device__ __forceinline__ int dot4(unsigned a, unsigned b, int c) {
    return __builtin_amdgcn_sdot4((int)a, (int)b, c, false);
}
#else
__device__ __forceinline__ int dot4(unsigned a, unsigned b, int c) {
    c += (int)(signed char)(a & 255u)         * (int)(signed char)(b & 255u);
    c += (int)(signed char)((a >> 8) & 255u)  * (int)(signed char)((b >> 8) & 255u);
    c += (int)(signed char)((a >> 16) & 255u) * (int)(signed char)((b >> 16) & 255u);
    c += (int)(signed char)(a >> 24)          * (int)(signed char)(b >> 24);
    return c;
}
#endif

// LSQ forward scale, bit-exact vs reference: sg = s*g; s_eff = sg + (s - sg)
__device__ __forceinline__ float seff(float s, float gf) {
    float sg = s * gf;
    return sg + (s - sg);
}
// Markstein correctly-rounded f32 division (rs = RN(1/s)), then clamp to
// [-128,127] (== clamp-after-round at integer bounds), then round-half-even
// via the f32 magic-add: low byte of bits(y + 1.5*2^23) is (q & 255).
__device__ __forceinline__ unsigned q8(float v, float s, float rs) {
    float q0 = v * rs;
    float r  = fmaf(-s, q0, v);
    float y  = fmaf(r, rs, q0);          // == RN(v/s)
    y = fminf(fmaxf(y, -128.f), 127.f);
    float t = y + 12582912.0f;           // 1.5*2^23, RNE to integer
    return __float_as_uint(t);           // low byte = q & 255
}
// round-half-even(acc * r) in one f64 fma against the 1.5*2^52 magic;
// identical to rint((double)acc*r): boundaries are >=1e-8 away, error <=1e-13.
__device__ __forceinline__ int mround(int acc, double r) {
    double t = fma((double)acc, r, 6755399441055744.0);
    return (int)__double_as_longlong(t);     // lo32 = integer (2's complement)
}

extern "C" __global__ __launch_bounds__(256, 4)
void qcnn_fused(const float* __restrict__ x,  const float* __restrict__ w1,
                const float* __restrict__ w2, const float* __restrict__ fcw,
                const float* __restrict__ fcb,
                const float* __restrict__ s_in, const float* __restrict__ s_w1,
                const float* __restrict__ s_a1, const float* __restrict__ s_w2,
                const float* __restrict__ s_a2, const float* __restrict__ s_fc,
                float* __restrict__ out, int B,
                float gx, float gw1, float ga1, float gw2, float ga2, float gfc)
{
    __shared__ unsigned xs[2][G*196];    // double-buffered quantized input
    __shared__ unsigned a1p[G*144];      // per pixel: 4 ic bytes of (a1-128)
    __shared__ unsigned a2p[G*50];       // 200 bytes of (a2-128) per image
    __shared__ unsigned w1pk[4][5][4];   // per ch,ky: evenA,evenB,oddA,oddB
    __shared__ unsigned w2p[8][9];       // per oc,tap: 4 ic bytes
    __shared__ unsigned fcp[10][50];     // fc weights i8 packed along k
    __shared__ int K2s[8];               // 128*sum(w2q[oc])
    __shared__ int K3s[10];              // 128*sum(fcq[o])
    __shared__ float fcbs[10];

    const int tid = threadIdx.x;
    const int g   = tid >> 5;
    const int t   = tid & 31;

    // scales: exact f32 replication of reference forward values
    const float sx  = seff(s_in[0], gx);
    const float sw1 = seff(s_w1[0], gw1);
    const float sa1 = seff(s_a1[0], ga1);
    const float sw2 = seff(s_w2[0], gw2);
    const float sa2 = seff(s_a2[0], ga2);
    const float sfc = seff(s_fc[0], gfc);
    const float rsx = 1.0f / sx;
    const float rw1 = 1.0f / sw1;
    const float rw2 = 1.0f / sw2;
    const float rfc = 1.0f / sfc;
    const double r1 = (double)sx  * (double)sw1 / (double)sa1;
    const double r2 = (double)sa1 * (double)sw2 / (double)sa2;
    const double r3 = (double)sa2 * (double)sfc;

    // ---------------- prep (once per block): weights -> packed i8 ---------
    if (tid < 80) {                       // w1 packs: 4ch x 5ky x 4 variants
        const int c = tid / 20, rem = tid % 20, ky = rem >> 2, vv = rem & 3;
        const float* wr = w1 + c*25 + ky*5;
        unsigned b[5];
        #pragma unroll
        for (int k = 0; k < 5; ++k) b[k] = q8(wr[k], sw1, rw1) & 255u;
        unsigned pk;
        if      (vv == 0) pk = b[0] | (b[1] << 8) | (b[2] << 16) | (b[3] << 24);
        else if (vv == 1) pk = b[4];
        else if (vv == 2) pk = (b[0] << 16) | (b[1] << 24);
        else              pk = b[2] | (b[3] << 8) | (b[4] << 16);
        w1pk[c][ky][vv] = pk;
    } else if (tid < 152) {               // w2 packs: 8oc x 9taps, ic-bytes
        const int d = tid - 80, oc = d / 9, tap = d % 9;
        unsigned pk = 0;
        #pragma unroll
        for (int ic = 0; ic < 4; ++ic)
            pk |= (q8(w2[oc*36 + ic*9 + tap], sw2, rw2) & 255u) << (8*ic);
        w2p[oc][tap] = pk;
    }
    if (tid < 10) fcbs[tid] = fcb[tid];
    for (int i = tid; i < 500; i += 256) { // fc packs: 10 x 50 dwords
        const int o = i / 50, kd = i % 50;
        const float* fr = fcw + o*200 + kd*4;
        unsigned pk = 0;
        #pragma unroll
        for (int k = 0; k < 4; ++k)
            pk |= (q8(fr[k], sfc, rfc) & 255u) << (8*k);
        fcp[o][kd] = pk;
    }
    __syncthreads();
    if (tid < 8) {                         // K2[oc] = 128*sum(w2q)
        int s = 0;
        #pragma unroll
        for (int d = 0; d < 9; ++d) s = dot4(w2p[tid][d], 0x01010101u, s);
        K2s[tid] = s << 7;
    } else if (tid < 18) {                 // K3[o] = 128*sum(fcq)
        const int o = tid - 8;
        int s = 0;
        for (int d = 0; d < 50; ++d) s = dot4(fcp[o][d], 0x01010101u, s);
        K3s[o] = s << 7;
    }

    const long long gbase = (long long)blockIdx.x * NG;

    // ---- stage a group's x into xs[buf] (quant -> i8 pack, coalesced) ----
    auto stage = [&](long long grp, int buf) {
        const int nimg = (B - (int)(grp * G) < G) ? (B - (int)(grp * G)) : G;
        if (nimg <= 0) return;
        const float4* xg = (const float4*)x + grp * (G * 196 / G) * G / 4 * 0 // dummy
                           ;
        (void)xg;
        const float4* xp = (const float4*)x + grp * (long long)(G * 196);
        unsigned* dst = xs[buf];
        if (nimg == G) {
            float4 v[6];
            #pragma unroll
            for (int k = 0; k < 6; ++k) v[k] = xp[tid + 256*k];
            const bool extra = tid < (G*196 - 6*256);   // 32 threads
            float4 v6;
            if (extra) v6 = xp[tid + 6*256];
            #pragma unroll
            for (int k = 0; k < 6; ++k) {
                float4 w = v[k];
                dst[tid + 256*k] =
                    (q8(w.x, sx, rsx) & 255u)         |
                    ((q8(w.y, sx, rsx) & 255u) << 8)  |
                    ((q8(w.z, sx, rsx) & 255u) << 16) |
                    (q8(w.w, sx, rsx) << 24);
            }
            if (extra) {
                dst[tid + 6*256] =
                    (q8(v6.x, sx, rsx) & 255u)         |
                    ((q8(v6.y, sx, rsx) & 255u) << 8)  |
                    ((q8(v6.z, sx, rsx) & 255u) << 16) |
                    (q8(v6.w, sx, rsx) << 24);
            }
        } else {
            const int nv = nimg * 196;
            for (int i = tid; i < nv; i += 256) {
                float4 w = xp[i];
                dst[i] = (q8(w.x, sx, rsx) & 255u)         |
                         ((q8(w.y, sx, rsx) & 255u) << 8)  |
                         ((q8(w.z, sx, rsx) & 255u) << 16) |
                         (q8(w.w, sx, rsx) << 24);
            }
        }
    };

    int cur = 0;
    stage(gbase, 0);

    for (int it = 0; it < NG; ++it) {
        const long long grp = gbase + it;
        if (grp * G >= B) break;                       // uniform per block
        const int nimg = (B - (int)(grp * G) < G) ? (B - (int)(grp * G)) : G;
        __syncthreads();                               // xs[cur] ready; a1p free

        if (it + 1 < NG) stage(grp + 1, cur ^ 1);      // overlap next load

        // ---- conv1: 96 tasks (y,c,half), 3 per lane, all 32 lanes -------
        if (g < nimg) {
            const unsigned* xb = &xs[cur][g*196];
            #pragma unroll
            for (int k = 0; k < 3; ++k) {
                const int tau = t + 32*k;
                const int y = tau >> 3, c = (tau >> 1) & 3, h = tau & 1;
                int acc[6] = {0,0,0,0,0,0};
                #pragma unroll
                for (int ky = 0; ky < 5; ++ky) {
                    const unsigned* rp = xb + (2*y + ky)*7 + 3*h;
                    const unsigned L0 = rp[0], L1 = rp[1], L2 = rp[2], L3 = rp[3];
                    const unsigned EA = w1pk[c][ky][0], EB = w1pk[c][ky][1];
                    const unsigned OA = w1pk[c][ky][2], OB = w1pk[c][ky][3];
                    acc[0] = dot4(L1, EB, dot4(L0, EA, acc[0]));
                    acc[1] = dot4(L1, OB, dot4(L0, OA, acc[1]));
                    acc[2] = dot4(L2, EB, dot4(L1, EA, acc[2]));
                    acc[3] = dot4(L2, OB, dot4(L1, OA, acc[3]));
                    acc[4] = dot4(L3, EB, dot4(L2, EA, acc[4]));
                    acc[5] = dot4(L3, OB, dot4(L2, OA, acc[5]));
                }
                unsigned char* dst = (unsigned char*)a1p + (g*144 + y*12 + 6*h)*4 + c;
                #pragma unroll
                for (int m = 0; m < 6; ++m) {
                    int q = mround(acc[m], r1);
                    q = min(max(q, 0), 255);
                    dst[4*m] = (unsigned char)(q - 128);
                }
            }
        }
        __syncthreads();

        // ---- conv2: block-wide tasks (img, oc, row): G*40 ----------------
        for (int tau = tid; tau < G*40; tau += 256) {
            const int img = tau / 40;
            const int rem = tau - img*40;
            const int oc  = rem / 5;
            const int y   = rem - oc*5;
            if (img >= nimg) break;
            unsigned wv[9];
            #pragma unroll
            for (int d = 0; d < 9; ++d) wv[d] = w2p[oc][d];
            const int k2 = K2s[oc];
            const unsigned* base = &a1p[img*144];
            unsigned rw[3][12];
            #pragma unroll
            for (int ky = 0; ky < 3; ++ky) {
                const uint4* rp = (const uint4*)&base[(2*y + ky)*12];
                uint4 A = rp[0], Bv = rp[1], Cv = rp[2];
                rw[ky][0]=A.x;  rw[ky][1]=A.y;  rw[ky][2]=A.z;  rw[ky][3]=A.w;
                rw[ky][4]=Bv.x; rw[ky][5]=Bv.y; rw[ky][6]=Bv.z; rw[ky][7]=Bv.w;
                rw[ky][8]=Cv.x; rw[ky][9]=Cv.y; rw[ky][10]=Cv.z; rw[ky][11]=Cv.w;
            }
            unsigned char* dst = (unsigned char*)a2p + img*200 + oc*25 + y*5;
            #pragma unroll
            for (int jx = 0; jx < 5; ++jx) {
                int acc = k2;
                #pragma unroll
                for (int ky = 0; ky < 3; ++ky)
                    #pragma unroll
                    for (int kx = 0; kx < 3; ++kx)
                        acc = dot4(rw[ky][2*jx + kx], wv[ky*3 + kx], acc);
                int q = mround(acc, r2);
                q = min(max(q, 0), 255);
                dst[jx] = (unsigned char)(q - 128);
            }
        }
        __syncthreads();

        // ---- FC: lane = (o, third-of-50-dwords) --------------------------
        if (g < nimg && t < 30) {
            const int part = t / 10;
            const int o    = t - part*10;
            const int k0   = part * 17;
            const int nk   = (part == 2) ? 16 : 17;
            int acc = 0;
            for (int ki = 0; ki < nk; ++ki) {
                const int k = k0 + ki;
                acc = dot4(a2p[g*50 + k], fcp[o][k], acc);
            }
            const int self0 = (g & 1) * 32 + o;
            const int s1 = __shfl(acc, self0 + 10);
            const int s2 = __shfl(acc, self0 + 20);
            if (part == 0) {
                const int total = acc + s1 + s2 + K3s[o];
                const double oo = (double)total * r3 + (double)fcbs[o];
                out[(grp*G + g)*10 + o] = (float)oo;
            }
        }
        cur ^= 1;
    }
}

extern "C" void kernel_launch(void* const* d_in, const int* in_sizes, int n_in,
                              void* d_out, int out_size, void* d_ws, size_t ws_size,
                              hipStream_t stream) {
    const float* x    = (const float*)d_in[0];
    const float* w1   = (const float*)d_in[1];
    const float* w2   = (const float*)d_in[2];
    const float* fcw  = (const float*)d_in[3];
    const float* fcb  = (const float*)d_in[4];
    const float* s_in = (const float*)d_in[5];
    const float* s_w1 = (const float*)d_in[6];
    const float* s_a1 = (const float*)d_in[7];
    const float* s_w2 = (const float*)d_in[8];
    const float* s_a2 = (const float*)d_in[9];
    const float* s_fc = (const float*)d_in[10];

    const int B = in_sizes[0] / 784;          // 65536
    // grad-scale factors g = 1/sqrt(n*qp), double->float exactly as reference
    const float gx  = (float)(1.0 / sqrt((double)B * 784.0 * 127.0));
    const float gw1 = (float)(1.0 / sqrt(100.0 * 127.0));
    const float ga1 = (float)(1.0 / sqrt((double)B * 576.0 * 255.0));
    const float gw2 = (float)(1.0 / sqrt(288.0 * 127.0));
    const float ga2 = (float)(1.0 / sqrt((double)B * 200.0 * 255.0));
    const float gfc = (float)(1.0 / sqrt(2000.0 * 127.0));

    const int imgs_per_block = G * NG;
    const int grid = (B + imgs_per_block - 1) / imgs_per_block;   // 2048
    qcnn_fused<<<grid, 256, 0, stream>>>(x, w1, w2, fcw, fcb,
                                         s_in, s_w1, s_a1, s_w2, s_a2, s_fc,
                                         (float*)d_out, B,
                                         gx, gw1, ga1, gw2, ga2, gfc);
}

// Round 5
// 59.129 us; speedup vs baseline: 3.3236x; 1.0833x over previous
//
#include <hip/hip_runtime.h>
#include <math.h>

#define G  8   // images per group (32 threads/image, 256-thread block)
#define NG 8   // groups per block (persistent loop) -> grid = 1024 = 4/CU

// ---- int8 dot4: D = c + sum(a.i8[i] * b.i8[i]) -------------------------
#if __has_builtin(__builtin_amdgcn_sdot4)
__device__ __forceinline__ int dot4(unsigned a, unsigned b, int c) {
    return __builtin_amdgcn_sdot4((int)a, (int)b, c, false);
}
#else
__device__ __forceinline__ int dot4(unsigned a, unsigned b, int c) {
    c += (int)(signed char)(a & 255u)         * (int)(signed char)(b & 255u);
    c += (int)(signed char)((a >> 8) & 255u)  * (int)(signed char)((b >> 8) & 255u);
    c += (int)(signed char)((a >> 16) & 255u) * (int)(signed char)((b >> 16) & 255u);
    c += (int)(signed char)(a >> 24)          * (int)(signed char)(b >> 24);
    return c;
}
#endif

// LSQ forward scale, bit-exact vs reference: sg = s*g; s_eff = sg + (s - sg)
__device__ __forceinline__ float seff(float s, float gf) {
    float sg = s * gf;
    return sg + (s - sg);
}
// Markstein correctly-rounded f32 division (rs = RN(1/s)), clamp to
// [-128,127] (== clamp-after-round at integer bounds), round-half-even
// via f32 magic-add: low byte of bits(y + 1.5*2^23) is (q & 255).
__device__ __forceinline__ unsigned q8(float v, float s, float rs) {
    float q0 = v * rs;
    float r  = fmaf(-s, q0, v);
    float y  = fmaf(r, rs, q0);          // == RN(v/s)
    y = fminf(fmaxf(y, -128.f), 127.f);
    float t = y + 12582912.0f;           // 1.5*2^23, RNE to integer
    return __float_as_uint(t);           // low byte = q & 255
}
__device__ __forceinline__ unsigned pack4(unsigned a, unsigned b, unsigned c, unsigned d) {
    return (a & 255u) | ((b & 255u) << 8) | ((c & 255u) << 16) | (d << 24);
}
// round-half-even(acc * r) via one f64 fma against 1.5*2^52 magic;
// identical to rint((double)acc*r): boundaries >=1e-8 away, error <=1e-13.
__device__ __forceinline__ int mround(int acc, double r) {
    double t = fma((double)acc, r, 6755399441055744.0);
    return (int)__double_as_longlong(t);     // lo32 = integer (2's complement)
}

extern "C" __global__ __launch_bounds__(256, 4)
void qcnn_fused(const float* __restrict__ x,  const float* __restrict__ w1,
                const float* __restrict__ w2, const float* __restrict__ fcw,
                const float* __restrict__ fcb,
                const float* __restrict__ s_in, const float* __restrict__ s_w1,
                const float* __restrict__ s_a1, const float* __restrict__ s_w2,
                const float* __restrict__ s_a2, const float* __restrict__ s_fc,
                float* __restrict__ out, int B,
                float gx, float gw1, float ga1, float gw2, float ga2, float gfc)
{
    __shared__ unsigned xs[2][G*196];              // double-buffered quantized x
    __shared__ unsigned a1p[G*144];                // per pixel: 4 ic bytes (a1-128)
    __shared__ unsigned a2p[G*50];                 // 200 bytes (a2-128) per image
    __shared__ __align__(16) unsigned w1pk[4][5][4]; // per c,ky: EA,EB,OA,OB
    __shared__ unsigned w2p[8][9];                 // per oc,tap: 4 ic bytes
    __shared__ unsigned fcp[10][50];               // fc weights i8 packed along k
    __shared__ int K2s[8];                         // 128*sum(w2q[oc])
    __shared__ int K3s[10];                        // 128*sum(fcq[o])
    __shared__ float fcbs[10];

    const int tid = threadIdx.x;
    const int g   = tid >> 5;
    const int t   = tid & 31;

    // scales: exact f32 replication of reference forward values
    const float sx  = seff(s_in[0], gx);
    const float sw1 = seff(s_w1[0], gw1);
    const float sa1 = seff(s_a1[0], ga1);
    const float sw2 = seff(s_w2[0], gw2);
    const float sa2 = seff(s_a2[0], ga2);
    const float sfc = seff(s_fc[0], gfc);
    const float rsx = 1.0f / sx;
    const float rw1 = 1.0f / sw1;
    const float rw2 = 1.0f / sw2;
    const float rfc = 1.0f / sfc;
    const double r1 = (double)sx  * (double)sw1 / (double)sa1;
    const double r2 = (double)sa1 * (double)sw2 / (double)sa2;
    const double r3 = (double)sa2 * (double)sfc;

    const long long gbase = (long long)blockIdx.x * NG;

    // ---- async staging: load phase (issue only) + write phase (quant) ----
    float4 Rv0, Rv1, Rv2, Rv3, Rv4, Rv5, Rv6;
    auto stage_load = [&](long long grp) {
        const int nimg = (B - (int)(grp * G) < G) ? (B - (int)(grp * G)) : G;
        if (nimg != G) return;                       // tail: sync path in write
        const float4* xp = (const float4*)x + grp * (long long)(G * 196);
        Rv0 = xp[tid];          Rv1 = xp[tid + 256]; Rv2 = xp[tid + 512];
        Rv3 = xp[tid + 768];    Rv4 = xp[tid + 1024];Rv5 = xp[tid + 1280];
        if (tid < 32) Rv6 = xp[tid + 1536];
    };
    auto stage_write = [&](long long grp, int buf) {
        const int nimg = (B - (int)(grp * G) < G) ? (B - (int)(grp * G)) : G;
        if (nimg <= 0) return;
        unsigned* dst = xs[buf];
        if (nimg == G) {
            float4 v;
            v = Rv0; dst[tid]        = pack4(q8(v.x,sx,rsx), q8(v.y,sx,rsx), q8(v.z,sx,rsx), q8(v.w,sx,rsx));
            v = Rv1; dst[tid + 256]  = pack4(q8(v.x,sx,rsx), q8(v.y,sx,rsx), q8(v.z,sx,rsx), q8(v.w,sx,rsx));
            v = Rv2; dst[tid + 512]  = pack4(q8(v.x,sx,rsx), q8(v.y,sx,rsx), q8(v.z,sx,rsx), q8(v.w,sx,rsx));
            v = Rv3; dst[tid + 768]  = pack4(q8(v.x,sx,rsx), q8(v.y,sx,rsx), q8(v.z,sx,rsx), q8(v.w,sx,rsx));
            v = Rv4; dst[tid + 1024] = pack4(q8(v.x,sx,rsx), q8(v.y,sx,rsx), q8(v.z,sx,rsx), q8(v.w,sx,rsx));
            v = Rv5; dst[tid + 1280] = pack4(q8(v.x,sx,rsx), q8(v.y,sx,rsx), q8(v.z,sx,rsx), q8(v.w,sx,rsx));
            if (tid < 32) {
                v = Rv6;
                dst[tid + 1536] = pack4(q8(v.x,sx,rsx), q8(v.y,sx,rsx), q8(v.z,sx,rsx), q8(v.w,sx,rsx));
            }
        } else {
            const float4* xp = (const float4*)x + grp * (long long)(G * 196);
            const int nv = nimg * 196;
            for (int i = tid; i < nv; i += 256) {
                float4 v = xp[i];
                dst[i] = pack4(q8(v.x,sx,rsx), q8(v.y,sx,rsx), q8(v.z,sx,rsx), q8(v.w,sx,rsx));
            }
        }
    };

    // start group-0 x loads before anything else (HBM latency under prep)
    stage_load(gbase);

    // ---------------- prep (once per block): weights -> packed i8 ---------
    if (tid < 80) {                       // w1 packs: 4ch x 5ky x 4 variants
        const int c = tid / 20, rem = tid % 20, ky = rem >> 2, vv = rem & 3;
        const float* wr = w1 + c*25 + ky*5;
        unsigned b[5];
        #pragma unroll
        for (int k = 0; k < 5; ++k) b[k] = q8(wr[k], sw1, rw1) & 255u;
        unsigned pk;
        if      (vv == 0) pk = b[0] | (b[1] << 8) | (b[2] << 16) | (b[3] << 24);
        else if (vv == 1) pk = b[4];
        else if (vv == 2) pk = (b[0] << 16) | (b[1] << 24);
        else              pk = b[2] | (b[3] << 8) | (b[4] << 16);
        w1pk[c][ky][vv] = pk;
    } else if (tid < 152) {               // w2 packs: 8oc x 9taps, ic-bytes
        const int d = tid - 80, oc = d / 9, tap = d % 9;
        unsigned pk = 0;
        #pragma unroll
        for (int ic = 0; ic < 4; ++ic)
            pk |= (q8(w2[oc*36 + ic*9 + tap], sw2, rw2) & 255u) << (8*ic);
        w2p[oc][tap] = pk;
    }
    if (tid < 10) fcbs[tid] = fcb[tid];
    for (int i = tid; i < 500; i += 256) { // fc packs: 10 x 50 dwords
        const int o = i / 50, kd = i % 50;
        const float* fr = fcw + o*200 + kd*4;
        unsigned pk = pack4(q8(fr[0],sfc,rfc), q8(fr[1],sfc,rfc),
                            q8(fr[2],sfc,rfc), q8(fr[3],sfc,rfc));
        fcp[o][kd] = pk;
    }
    __syncthreads();
    if (tid < 8) {                         // K2[oc] = 128*sum(w2q)
        int s = 0;
        #pragma unroll
        for (int d = 0; d < 9; ++d) s = dot4(w2p[tid][d], 0x01010101u, s);
        K2s[tid] = s << 7;
    } else if (tid < 18) {                 // K3[o] = 128*sum(fcq)
        const int o = tid - 8;
        int s = 0;
        for (int d = 0; d < 50; ++d) s = dot4(fcp[o][d], 0x01010101u, s);
        K3s[o] = s << 7;
    }
    stage_write(gbase, 0);                 // vmcnt wait + quant + LDS write
    __syncthreads();                       // xs[0], weights, K2/K3 all ready

    int cur = 0;
    for (int it = 0; it < NG; ++it) {
        const long long grp = gbase + it;
        if (grp * G >= B) break;                       // uniform per block
        const int nimg = (B - (int)(grp * G) < G) ? (B - (int)(grp * G)) : G;

        if (it + 1 < NG) stage_load(grp + 1);          // issue loads, no wait

        // ---- conv1: lane = fixed (c,h), y = y0+4k; 180 dot4 / lane ------
        if (g < nimg) {
            const int c  = t & 3;
            const int h  = (t >> 2) & 1;
            const int y0 = t >> 3;                     // 0..3
            uint4 W[5];
            #pragma unroll
            for (int ky = 0; ky < 5; ++ky)
                W[ky] = *(const uint4*)&w1pk[c][ky][0];  // EA,EB,OA,OB
            const unsigned* xb = &xs[cur][g*196];
            #pragma unroll
            for (int k = 0; k < 3; ++k) {
                const int y = y0 + 4*k;
                int acc[6] = {0,0,0,0,0,0};
                #pragma unroll
                for (int ky = 0; ky < 5; ++ky) {
                    const unsigned* rp = xb + (2*y + ky)*7 + 3*h;
                    const unsigned L0 = rp[0], L1 = rp[1], L2 = rp[2], L3 = rp[3];
                    acc[0] = dot4(L1, W[ky].y, dot4(L0, W[ky].x, acc[0]));
                    acc[1] = dot4(L1, W[ky].w, dot4(L0, W[ky].z, acc[1]));
                    acc[2] = dot4(L2, W[ky].y, dot4(L1, W[ky].x, acc[2]));
                    acc[3] = dot4(L2, W[ky].w, dot4(L1, W[ky].z, acc[3]));
                    acc[4] = dot4(L3, W[ky].y, dot4(L2, W[ky].x, acc[4]));
                    acc[5] = dot4(L3, W[ky].w, dot4(L2, W[ky].z, acc[5]));
                }
                unsigned char* dst = (unsigned char*)a1p + (g*144 + y*12 + 6*h)*4 + c;
                #pragma unroll
                for (int m = 0; m < 6; ++m) {
                    int q = mround(acc[m], r1);
                    q = min(max(q, 0), 255);
                    dst[4*m] = (unsigned char)(q - 128);
                }
            }
        }
        __syncthreads();                               // a1p ready

        // ---- conv2: block-wide tasks (img, oc, row): G*40 ----------------
        for (int tau = tid; tau < G*40; tau += 256) {
            const int img = tau / 40;
            const int rem = tau - img*40;
            const int oc  = rem / 5;
            const int y   = rem - oc*5;
            if (img >= nimg) break;
            unsigned wv[9];
            #pragma unroll
            for (int d = 0; d < 9; ++d) wv[d] = w2p[oc][d];
            const int k2 = K2s[oc];
            const unsigned* base = &a1p[img*144];
            unsigned rw[3][12];
            #pragma unroll
            for (int ky = 0; ky < 3; ++ky) {
                const uint4* rp = (const uint4*)&base[(2*y + ky)*12];
                uint4 A = rp[0], Bv = rp[1], Cv = rp[2];
                rw[ky][0]=A.x;  rw[ky][1]=A.y;  rw[ky][2]=A.z;  rw[ky][3]=A.w;
                rw[ky][4]=Bv.x; rw[ky][5]=Bv.y; rw[ky][6]=Bv.z; rw[ky][7]=Bv.w;
                rw[ky][8]=Cv.x; rw[ky][9]=Cv.y; rw[ky][10]=Cv.z; rw[ky][11]=Cv.w;
            }
            unsigned char* dst = (unsigned char*)a2p + img*200 + oc*25 + y*5;
            #pragma unroll
            for (int jx = 0; jx < 5; ++jx) {
                int acc = k2;
                #pragma unroll
                for (int ky = 0; ky < 3; ++ky)
                    #pragma unroll
                    for (int kx = 0; kx < 3; ++kx)
                        acc = dot4(rw[ky][2*jx + kx], wv[ky*3 + kx], acc);
                int q = mround(acc, r2);
                q = min(max(q, 0), 255);
                dst[jx] = (unsigned char)(q - 128);
            }
        }

        if (it + 1 < NG) stage_write(grp + 1, cur ^ 1); // vmcnt + quant + write
        __syncthreads();                               // a2p + xs[next] ready

        // ---- FC: lane = (o, third-of-50-dwords) --------------------------
        if (g < nimg && t < 30) {
            const int part = t / 10;
            const int o    = t - part*10;
            const int k0   = part * 17;
            const int nk   = (part == 2) ? 16 : 17;
            int acc = 0;
            for (int ki = 0; ki < nk; ++ki) {
                const int k = k0 + ki;
                acc = dot4(a2p[g*50 + k], fcp[o][k], acc);
            }
            const int self0 = (g & 1) * 32 + o;
            const int s1 = __shfl(acc, self0 + 10);
            const int s2 = __shfl(acc, self0 + 20);
            if (part == 0) {
                const int total = acc + s1 + s2 + K3s[o];
                const double oo = (double)total * r3 + (double)fcbs[o];
                out[(grp*G + g)*10 + o] = (float)oo;
            }
        }
        // no loop-top barrier needed: next conv1 reads xs[cur^1] (written
        // before the barrier above); a1p overwrite is fenced by that same
        // barrier + conv2's position; a2p overwrite is two barriers away.
        cur ^= 1;
    }
}

extern "C" void kernel_launch(void* const* d_in, const int* in_sizes, int n_in,
                              void* d_out, int out_size, void* d_ws, size_t ws_size,
                              hipStream_t stream) {
    const float* x    = (const float*)d_in[0];
    const float* w1   = (const float*)d_in[1];
    const float* w2   = (const float*)d_in[2];
    const float* fcw  = (const float*)d_in[3];
    const float* fcb  = (const float*)d_in[4];
    const float* s_in = (const float*)d_in[5];
    const float* s_w1 = (const float*)d_in[6];
    const float* s_a1 = (const float*)d_in[7];
    const float* s_w2 = (const float*)d_in[8];
    const float* s_a2 = (const float*)d_in[9];
    const float* s_fc = (const float*)d_in[10];

    const int B = in_sizes[0] / 784;          // 65536
    // grad-scale factors g = 1/sqrt(n*qp), double->float exactly as reference
    const float gx  = (float)(1.0 / sqrt((double)B * 784.0 * 127.0));
    const float gw1 = (float)(1.0 / sqrt(100.0 * 127.0));
    const float ga1 = (float)(1.0 / sqrt((double)B * 576.0 * 255.0));
    const float gw2 = (float)(1.0 / sqrt(288.0 * 127.0));
    const float ga2 = (float)(1.0 / sqrt((double)B * 200.0 * 255.0));
    const float gfc = (float)(1.0 / sqrt(2000.0 * 127.0));

    const int imgs_per_block = G * NG;        // 64
    const int grid = (B + imgs_per_block - 1) / imgs_per_block;   // 1024
    qcnn_fused<<<grid, 256, 0, stream>>>(x, w1, w2, fcw, fcb,
                                         s_in, s_w1, s_a1, s_w2, s_a2, s_fc,
                                         (float*)d_out, B,
                                         gx, gw1, ga1, gw2, ga2, gfc);
}

// Round 6
// 55.700 us; speedup vs baseline: 3.5282x; 1.0616x over previous
//
#include <hip/hip_runtime.h>
#include <math.h>

#define G  8   // images per block-iteration (one 32-lane group per image)
#define NG 8   // iterations per block -> 64 images/block, grid = 1024 = 4/CU

// ---- int8 dot4: D = c + sum(a.i8[i] * b.i8[i]) -------------------------
#if __has_builtin(__builtin_amdgcn_sdot4)
__device__ __forceinline__ int dot4(unsigned a, unsigned b, int c) {
    return __builtin_amdgcn_sdot4((int)a, (int)b, c, false);
}
#else
__device__ __forceinline__ int dot4(unsigned a, unsigned b, int c) {
    c += (int)(signed char)(a & 255u)         * (int)(signed char)(b & 255u);
    c += (int)(signed char)((a >> 8) & 255u)  * (int)(signed char)((b >> 8) & 255u);
    c += (int)(signed char)((a >> 16) & 255u) * (int)(signed char)((b >> 16) & 255u);
    c += (int)(signed char)(a >> 24)          * (int)(signed char)(b >> 24);
    return c;
}
#endif

// wave-internal LDS fence: orders this wave's LDS ops (compiler can't
// reorder memory ops across the asm; lgkmcnt(0) waits completion).
__device__ __forceinline__ void wave_fence() {
    asm volatile("s_waitcnt lgkmcnt(0)" ::: "memory");
}

// LSQ forward scale, bit-exact vs reference: sg = s*g; s_eff = sg + (s - sg)
__device__ __forceinline__ float seff(float s, float gf) {
    float sg = s * gf;
    return sg + (s - sg);
}
// Markstein correctly-rounded f32 division (rs = RN(1/s)), clamp to
// [-128,127] (== clamp-after-round at integer bounds), round-half-even
// via f32 magic-add: low byte of bits(y + 1.5*2^23) is (q & 255).
__device__ __forceinline__ unsigned q8(float v, float s, float rs) {
    float q0 = v * rs;
    float r  = fmaf(-s, q0, v);
    float y  = fmaf(r, rs, q0);          // == RN(v/s)
    y = fminf(fmaxf(y, -128.f), 127.f);
    float t = y + 12582912.0f;           // 1.5*2^23, RNE to integer
    return __float_as_uint(t);           // low byte = q & 255
}
__device__ __forceinline__ unsigned pack4(unsigned a, unsigned b, unsigned c, unsigned d) {
    return (a & 255u) | ((b & 255u) << 8) | ((c & 255u) << 16) | (d << 24);
}
// round-half-even(acc * r) via one f64 fma against 1.5*2^52 magic;
// identical to rint((double)acc*r): boundaries >=1e-8 away, error <=1e-13.
__device__ __forceinline__ int mround(int acc, double r) {
    double t = fma((double)acc, r, 6755399441055744.0);
    return (int)__double_as_longlong(t);     // lo32 = integer (2's complement)
}

extern "C" __global__ __launch_bounds__(256, 4)
void qcnn_fused(const float* __restrict__ x,  const float* __restrict__ w1,
                const float* __restrict__ w2, const float* __restrict__ fcw,
                const float* __restrict__ fcb,
                const float* __restrict__ s_in, const float* __restrict__ s_w1,
                const float* __restrict__ s_a1, const float* __restrict__ s_w2,
                const float* __restrict__ s_a2, const float* __restrict__ s_fc,
                float* __restrict__ out, int B,
                float gx, float gw1, float ga1, float gw2, float ga2, float gfc)
{
    __shared__ unsigned xs[2][G*196];              // double-buffered quantized x
    __shared__ unsigned a1p[G*144];                // per pixel: 4 ic bytes (a1-128)
    __shared__ unsigned a2p[G*50];                 // 200 bytes (a2-128) per image
    __shared__ __align__(16) unsigned w1pk[4][5][4]; // per c,ky: EA,EB,OA,OB
    __shared__ unsigned w2p[8][9];                 // per oc,tap: 4 ic bytes
    __shared__ unsigned fcp[10][50];               // fc weights i8 packed along k
    __shared__ int K2s[8];                         // 128*sum(w2q[oc])
    __shared__ int K3s[10];                        // 128*sum(fcq[o])
    __shared__ float fcbs[10];

    const int tid = threadIdx.x;
    const int g   = tid >> 5;    // image slot (0..7), 2 slots per wave
    const int t   = tid & 31;    // lane within group

    // scales: exact f32 replication of reference forward values
    const float sx  = seff(s_in[0], gx);
    const float sw1 = seff(s_w1[0], gw1);
    const float sa1 = seff(s_a1[0], ga1);
    const float sw2 = seff(s_w2[0], gw2);
    const float sa2 = seff(s_a2[0], ga2);
    const float sfc = seff(s_fc[0], gfc);
    const float rsx = 1.0f / sx;
    const float rw1 = 1.0f / sw1;
    const float rw2 = 1.0f / sw2;
    const float rfc = 1.0f / sfc;
    const double r1 = (double)sx  * (double)sw1 / (double)sa1;
    const double r2 = (double)sa1 * (double)sw2 / (double)sa2;
    const double r3 = (double)sa2 * (double)sfc;

    const long long gbase = (long long)blockIdx.x * NG;

    // ---- group-local async staging: issue loads early, write late -------
    float4 Rv0, Rv1, Rv2, Rv3, Rv4, Rv5, Rv6;
    auto stage_load = [&](long long grp) {
        const long long img = grp * G + g;
        if (img >= B) return;
        const float4* xp = (const float4*)x + img * 196;
        Rv0 = xp[t];        Rv1 = xp[t + 32];  Rv2 = xp[t + 64];
        Rv3 = xp[t + 96];   Rv4 = xp[t + 128]; Rv5 = xp[t + 160];
        if (t < 4) Rv6 = xp[t + 192];
    };
    auto stage_write = [&](long long grp, int buf) {
        const long long img = grp * G + g;
        if (img >= B) return;
        unsigned* dst = &xs[buf][g*196];
        float4 v;
        v = Rv0; dst[t]       = pack4(q8(v.x,sx,rsx), q8(v.y,sx,rsx), q8(v.z,sx,rsx), q8(v.w,sx,rsx));
        v = Rv1; dst[t + 32]  = pack4(q8(v.x,sx,rsx), q8(v.y,sx,rsx), q8(v.z,sx,rsx), q8(v.w,sx,rsx));
        v = Rv2; dst[t + 64]  = pack4(q8(v.x,sx,rsx), q8(v.y,sx,rsx), q8(v.z,sx,rsx), q8(v.w,sx,rsx));
        v = Rv3; dst[t + 96]  = pack4(q8(v.x,sx,rsx), q8(v.y,sx,rsx), q8(v.z,sx,rsx), q8(v.w,sx,rsx));
        v = Rv4; dst[t + 128] = pack4(q8(v.x,sx,rsx), q8(v.y,sx,rsx), q8(v.z,sx,rsx), q8(v.w,sx,rsx));
        v = Rv5; dst[t + 160] = pack4(q8(v.x,sx,rsx), q8(v.y,sx,rsx), q8(v.z,sx,rsx), q8(v.w,sx,rsx));
        if (t < 4) {
            v = Rv6;
            dst[t + 192] = pack4(q8(v.x,sx,rsx), q8(v.y,sx,rsx), q8(v.z,sx,rsx), q8(v.w,sx,rsx));
        }
    };

    // start group-0 x loads before anything else (HBM latency under prep)
    stage_load(gbase);

    // ---------------- prep (once per block): weights -> packed i8 ---------
    if (tid < 80) {                       // w1 packs: 4ch x 5ky x 4 variants
        const int c = tid / 20, rem = tid % 20, ky = rem >> 2, vv = rem & 3;
        const float* wr = w1 + c*25 + ky*5;
        unsigned b[5];
        #pragma unroll
        for (int k = 0; k < 5; ++k) b[k] = q8(wr[k], sw1, rw1) & 255u;
        unsigned pk;
        if      (vv == 0) pk = b[0] | (b[1] << 8) | (b[2] << 16) | (b[3] << 24);
        else if (vv == 1) pk = b[4];
        else if (vv == 2) pk = (b[0] << 16) | (b[1] << 24);
        else              pk = b[2] | (b[3] << 8) | (b[4] << 16);
        w1pk[c][ky][vv] = pk;
    } else if (tid < 152) {               // w2 packs: 8oc x 9taps, ic-bytes
        const int d = tid - 80, oc = d / 9, tap = d % 9;
        unsigned pk = 0;
        #pragma unroll
        for (int ic = 0; ic < 4; ++ic)
            pk |= (q8(w2[oc*36 + ic*9 + tap], sw2, rw2) & 255u) << (8*ic);
        w2p[oc][tap] = pk;
    }
    if (tid < 10) fcbs[tid] = fcb[tid];
    for (int i = tid; i < 500; i += 256) { // fc packs: 10 x 50 dwords
        const int o = i / 50, kd = i % 50;
        const float* fr = fcw + o*200 + kd*4;
        fcp[o][kd] = pack4(q8(fr[0],sfc,rfc), q8(fr[1],sfc,rfc),
                           q8(fr[2],sfc,rfc), q8(fr[3],sfc,rfc));
    }
    __syncthreads();
    if (tid < 8) {                         // K2[oc] = 128*sum(w2q)
        int s = 0;
        #pragma unroll
        for (int d = 0; d < 9; ++d) s = dot4(w2p[tid][d], 0x01010101u, s);
        K2s[tid] = s << 7;
    } else if (tid < 18) {                 // K3[o] = 128*sum(fcq)
        const int o = tid - 8;
        int s = 0;
        for (int d = 0; d < 50; ++d) s = dot4(fcp[o][d], 0x01010101u, s);
        K3s[o] = s << 7;
    }
    __syncthreads();                       // weights + K2/K3 visible to all
    stage_write(gbase, 0);
    wave_fence();                          // xs[0] (this group) ready

    int cur = 0;
    for (int it = 0; it < NG; ++it) {
        const long long grp = gbase + it;
        if (grp * G >= B) break;
        const bool act = (grp * G + g) < B;

        if (it + 1 < NG) stage_load(grp + 1);   // issue loads, no wait

        // ---- conv1: lane = fixed (c,h), y = y0+4k; group-local ----------
        if (act) {
            const int c  = t & 3;
            const int h  = (t >> 2) & 1;
            const int y0 = t >> 3;                  // 0..3
            uint4 W[5];
            #pragma unroll
            for (int ky = 0; ky < 5; ++ky)
                W[ky] = *(const uint4*)&w1pk[c][ky][0];  // EA,EB,OA,OB
            const unsigned* xb = &xs[cur][g*196];
            #pragma unroll
            for (int k = 0; k < 3; ++k) {
                const int y = y0 + 4*k;
                int acc[6] = {0,0,0,0,0,0};
                #pragma unroll
                for (int ky = 0; ky < 5; ++ky) {
                    const unsigned* rp = xb + (2*y + ky)*7 + 3*h;
                    const unsigned L0 = rp[0], L1 = rp[1], L2 = rp[2], L3 = rp[3];
                    acc[0] = dot4(L1, W[ky].y, dot4(L0, W[ky].x, acc[0]));
                    acc[1] = dot4(L1, W[ky].w, dot4(L0, W[ky].z, acc[1]));
                    acc[2] = dot4(L2, W[ky].y, dot4(L1, W[ky].x, acc[2]));
                    acc[3] = dot4(L2, W[ky].w, dot4(L1, W[ky].z, acc[3]));
                    acc[4] = dot4(L3, W[ky].y, dot4(L2, W[ky].x, acc[4]));
                    acc[5] = dot4(L3, W[ky].w, dot4(L2, W[ky].z, acc[5]));
                }
                unsigned char* dst = (unsigned char*)a1p + (g*144 + y*12 + 6*h)*4 + c;
                #pragma unroll
                for (int m = 0; m < 6; ++m) {
                    int q = mround(acc[m], r1);
                    q = min(max(q, 0), 255);
                    dst[4*m] = (unsigned char)(q - 128);
                }
            }
        }
        wave_fence();                           // a1p (this group) ready

        // ---- conv2: group-local; lane = (oc = t>>2, y = t&3), +y=4 ------
        if (act) {
            const int oc = t >> 2;
            unsigned wv[9];
            #pragma unroll
            for (int d = 0; d < 9; ++d) wv[d] = w2p[oc][d];
            const int k2 = K2s[oc];
            const unsigned* base = &a1p[g*144];
            unsigned char* dstb = (unsigned char*)a2p + g*200 + oc*25;
            #pragma unroll
            for (int pass = 0; pass < 2; ++pass) {
                const int y = pass ? 4 : (t & 3);
                if (pass && (t & 3) != 0) break;
                unsigned rw[3][12];
                #pragma unroll
                for (int ky = 0; ky < 3; ++ky) {
                    const uint4* rp = (const uint4*)&base[(2*y + ky)*12];
                    uint4 A = rp[0], Bv = rp[1], Cv = rp[2];
                    rw[ky][0]=A.x;  rw[ky][1]=A.y;  rw[ky][2]=A.z;  rw[ky][3]=A.w;
                    rw[ky][4]=Bv.x; rw[ky][5]=Bv.y; rw[ky][6]=Bv.z; rw[ky][7]=Bv.w;
                    rw[ky][8]=Cv.x; rw[ky][9]=Cv.y; rw[ky][10]=Cv.z; rw[ky][11]=Cv.w;
                }
                #pragma unroll
                for (int jx = 0; jx < 5; ++jx) {
                    int acc = k2;
                    #pragma unroll
                    for (int ky = 0; ky < 3; ++ky)
                        #pragma unroll
                        for (int kx = 0; kx < 3; ++kx)
                            acc = dot4(rw[ky][2*jx + kx], wv[ky*3 + kx], acc);
                    int q = mround(acc, r2);
                    q = min(max(q, 0), 255);
                    dstb[y*5 + jx] = (unsigned char)(q - 128);
                }
            }
        }
        wave_fence();                           // a2p (this group) ready

        // ---- FC: group-local; lane = (o, third-of-50-dwords) ------------
        if (act && t < 30) {
            const int part = t / 10;
            const int o    = t - part*10;
            const int k0   = part * 17;
            const int nk   = (part == 2) ? 16 : 17;
            int acc = 0;
            for (int ki = 0; ki < nk; ++ki) {
                const int k = k0 + ki;
                acc = dot4(a2p[g*50 + k], fcp[o][k], acc);
            }
            const int self0 = (g & 1) * 32 + o;
            const int s1 = __shfl(acc, self0 + 10);
            const int s2 = __shfl(acc, self0 + 20);
            if (part == 0) {
                const int total = acc + s1 + s2 + K3s[o];
                const double oo = (double)total * r3 + (double)fcbs[o];
                out[(grp*G + g)*10 + o] = (float)oo;
            }
        }

        if (it + 1 < NG) {
            stage_write(grp + 1, cur ^ 1);      // vmcnt wait + quant + write
            wave_fence();                       // xs[next] ready for conv1
        }
        cur ^= 1;
    }
}

extern "C" void kernel_launch(void* const* d_in, const int* in_sizes, int n_in,
                              void* d_out, int out_size, void* d_ws, size_t ws_size,
                              hipStream_t stream) {
    const float* x    = (const float*)d_in[0];
    const float* w1   = (const float*)d_in[1];
    const float* w2   = (const float*)d_in[2];
    const float* fcw  = (const float*)d_in[3];
    const float* fcb  = (const float*)d_in[4];
    const float* s_in = (const float*)d_in[5];
    const float* s_w1 = (const float*)d_in[6];
    const float* s_a1 = (const float*)d_in[7];
    const float* s_w2 = (const float*)d_in[8];
    const float* s_a2 = (const float*)d_in[9];
    const float* s_fc = (const float*)d_in[10];

    const int B = in_sizes[0] / 784;          // 65536
    // grad-scale factors g = 1/sqrt(n*qp), double->float exactly as reference
    const float gx  = (float)(1.0 / sqrt((double)B * 784.0 * 127.0));
    const float gw1 = (float)(1.0 / sqrt(100.0 * 127.0));
    const float ga1 = (float)(1.0 / sqrt((double)B * 576.0 * 255.0));
    const float gw2 = (float)(1.0 / sqrt(288.0 * 127.0));
    const float ga2 = (float)(1.0 / sqrt((double)B * 200.0 * 255.0));
    const float gfc = (float)(1.0 / sqrt(2000.0 * 127.0));

    const int imgs_per_block = G * NG;        // 64
    const int grid = (B + imgs_per_block - 1) / imgs_per_block;   // 1024
    qcnn_fused<<<grid, 256, 0, stream>>>(x, w1, w2, fcw, fcb,
                                         s_in, s_w1, s_a1, s_w2, s_a2, s_fc,
                                         (float*)d_out, B,
                                         gx, gw1, ga1, gw2, ga2, gfc);
}